// Round 1
// baseline (85.213 us; speedup 1.0000x reference)
//
#include <hip/hip_runtime.h>
#include <stdint.h>

typedef __bf16 bf16x8 __attribute__((ext_vector_type(8)));
typedef float f32x4 __attribute__((ext_vector_type(4)));

#define N_ROWS 4096
#define KD 128
#define BM 64
#define BN 64
#define LDA 136   // LDS row stride in bf16 elems: 128 + 8 pad (272 B) -> 2-way bank aliasing (free)
#define NCHUNK 4
#define CHUNK 1024

__device__ __forceinline__ unsigned short f32_to_bf16_rne(float f) {
    union { float f; uint32_t u; } v; v.f = f;
    uint32_t u = v.u;
    return (unsigned short)((u + 0x7FFFu + ((u >> 16) & 1u)) >> 16);
}

// One wave per row: L2-normalize, round to bf16 (RNE), pack 2 elems/lane.
__global__ __launch_bounds__(256) void normalize_kernel(const float* __restrict__ E,
                                                        unsigned short* __restrict__ out) {
    const int wave = threadIdx.x >> 6;
    const int lane = threadIdx.x & 63;
    const int row = blockIdx.x * 4 + wave;
    const float2 v = *(const float2*)&E[row * KD + lane * 2];
    float s = v.x * v.x + v.y * v.y;
#pragma unroll
    for (int m = 1; m < 64; m <<= 1) s += __shfl_xor(s, m, 64);
    float inv = 0.0f;
    if (s > 0.0f) {
        inv = rsqrtf(s);
        inv = inv * (1.5f - 0.5f * s * inv * inv);  // Newton step: ~1e-7 rel err
    }
    const unsigned short a = f32_to_bf16_rne(v.x * inv);
    const unsigned short b = f32_to_bf16_rne(v.y * inv);
    ((uint32_t*)out)[row * (KD / 2) + lane] = ((uint32_t)b << 16) | a;
}

// Block = 64-row I-tile x 1024-col J-chunk. MFMA 16x16x32 bf16 Gram tiles with
// fused hardest-pos/neg epilogue; partial per-(row,chunk) min/max to ws.
__global__ __launch_bounds__(256) void gram_kernel(const unsigned short* __restrict__ Ebits,
                                                   const int* __restrict__ labels,
                                                   float* __restrict__ minpos_part,
                                                   float* __restrict__ maxneg_part) {
    __shared__ unsigned short As[BM * LDA];
    __shared__ unsigned short Bs[BN * LDA];
    __shared__ int ljs[BN];

    const int tid = threadIdx.x;
    const int itile = blockIdx.x & 63;
    const int chunk = blockIdx.x >> 6;
    const int ibase = itile * BM;
    const int cbase = chunk * CHUNK;

    // Stage A-tile: 64 rows x 128 bf16 = 1024 x uint4, coalesced.
    {
        const uint4* src = (const uint4*)(Ebits + (size_t)ibase * KD);
#pragma unroll
        for (int it = 0; it < 4; ++it) {
            const int li = tid + it * 256;
            const int r = li >> 4, c = li & 15;
            *(uint4*)&As[r * LDA + c * 8] = src[li];
        }
    }
    __syncthreads();

    const int wave = tid >> 6, lane = tid & 63;
    const int quad = lane >> 4, l15 = lane & 15;

    // A fragments: A[m=lane&15][k=quad*8+j], kept in regs for the whole chunk.
    bf16x8 afrag[4];
    const unsigned short* arow = &As[(wave * 16 + l15) * LDA + quad * 8];
#pragma unroll
    for (int s = 0; s < 4; ++s) afrag[s] = *(const bf16x8*)(arow + s * 32);

    int li_lab[4];
#pragma unroll
    for (int r = 0; r < 4; ++r) li_lab[r] = labels[ibase + wave * 16 + quad * 4 + r];

    float minpos[4] = {2.0f, 2.0f, 2.0f, 2.0f};    // dots are in [-1,1]; 2.0 = "no positive"
    float maxneg[4] = {-2.0f, -2.0f, -2.0f, -2.0f};

    for (int jt = 0; jt < CHUNK / BN; ++jt) {
        const int jbase = cbase + jt * BN;
        __syncthreads();  // prev iter's Bs reads done
        {
            const uint4* src = (const uint4*)(Ebits + (size_t)jbase * KD);
#pragma unroll
            for (int it = 0; it < 4; ++it) {
                const int li = tid + it * 256;
                const int r = li >> 4, c = li & 15;
                *(uint4*)&Bs[r * LDA + c * 8] = src[li];
            }
            if (tid < BN) ljs[tid] = labels[jbase + tid];
        }
        __syncthreads();

#pragma unroll
        for (int t = 0; t < 4; ++t) {
            const unsigned short* brow = &Bs[(t * 16 + l15) * LDA + quad * 8];
            f32x4 acc = {0.f, 0.f, 0.f, 0.f};
#pragma unroll
            for (int s = 0; s < 4; ++s) {
                const bf16x8 bfrag = *(const bf16x8*)(brow + s * 32);
                acc = __builtin_amdgcn_mfma_f32_16x16x32_bf16(afrag[s], bfrag, acc, 0, 0, 0);
            }
            // C/D layout: col = lane&15 (j), row = quad*4 + reg (i)  [m89/m91]
            const int jg = jbase + t * 16 + l15;
            const int lj = ljs[t * 16 + l15];
#pragma unroll
            for (int r = 0; r < 4; ++r) {
                const int ig = ibase + wave * 16 + quad * 4 + r;
                const float d = acc[r];
                const bool same = (lj == li_lab[r]);
                const float dp = (same && (ig != jg)) ? d : 2.0f;
                const float dn = same ? -2.0f : d;
                minpos[r] = fminf(minpos[r], dp);
                maxneg[r] = fmaxf(maxneg[r], dn);
            }
        }
    }

    // Reduce across the 16 lanes of each quad (cols); rows live in (quad,reg).
#pragma unroll
    for (int m = 1; m < 16; m <<= 1) {
#pragma unroll
        for (int r = 0; r < 4; ++r) {
            minpos[r] = fminf(minpos[r], __shfl_xor(minpos[r], m, 64));
            maxneg[r] = fmaxf(maxneg[r], __shfl_xor(maxneg[r], m, 64));
        }
    }
    if (l15 == 0) {
#pragma unroll
        for (int r = 0; r < 4; ++r) {
            const int row = ibase + wave * 16 + quad * 4 + r;
            minpos_part[row * NCHUNK + chunk] = minpos[r];
            maxneg_part[row * NCHUNK + chunk] = maxneg[r];
        }
    }
}

__global__ __launch_bounds__(256) void finalize_kernel(const float* __restrict__ minpos_part,
                                                       const float* __restrict__ maxneg_part,
                                                       float* __restrict__ out) {
    __shared__ float ssum[4];
    __shared__ int scnt[4];
    float sum = 0.f;
    int cnt = 0;
    for (int row = threadIdx.x; row < N_ROWS; row += 256) {
        float mp = 2.f, mn = -2.f;
#pragma unroll
        for (int c = 0; c < NCHUNK; ++c) {
            mp = fminf(mp, minpos_part[row * NCHUNK + c]);
            mn = fmaxf(mn, maxneg_part[row * NCHUNK + c]);
        }
        if (mp < 1.5f && mn > -1.5f) {  // valid: has >=1 positive and >=1 negative
            sum += fmaxf(0.f, mn - mp + 0.3f);  // relu(hp - hn + margin)
            cnt += 1;
        }
    }
#pragma unroll
    for (int m = 1; m < 64; m <<= 1) {
        sum += __shfl_xor(sum, m, 64);
        cnt += __shfl_xor(cnt, m, 64);
    }
    const int wave = threadIdx.x >> 6, lane = threadIdx.x & 63;
    if (lane == 0) { ssum[wave] = sum; scnt[wave] = cnt; }
    __syncthreads();
    if (threadIdx.x == 0) {
        const float S = ssum[0] + ssum[1] + ssum[2] + ssum[3];
        const int C = scnt[0] + scnt[1] + scnt[2] + scnt[3];
        out[0] = S / (float)(C > 0 ? C : 1);
    }
}

extern "C" void kernel_launch(void* const* d_in, const int* in_sizes, int n_in,
                              void* d_out, int out_size, void* d_ws, size_t ws_size,
                              hipStream_t stream) {
    const float* E = (const float*)d_in[0];
    const int* labels = (const int*)d_in[1];

    unsigned short* ebits = (unsigned short*)d_ws;                       // 1 MiB
    float* minpos_part = (float*)((char*)d_ws + (size_t)N_ROWS * KD * 2);  // 64 KiB
    float* maxneg_part = minpos_part + N_ROWS * NCHUNK;                  // 64 KiB
    float* out = (float*)d_out;

    normalize_kernel<<<N_ROWS / 4, 256, 0, stream>>>(E, ebits);
    gram_kernel<<<64 * NCHUNK, 256, 0, stream>>>(ebits, labels, minpos_part, maxneg_part);
    finalize_kernel<<<1, 256, 0, stream>>>(minpos_part, maxneg_part, out);
}

// Round 2
// 78.344 us; speedup vs baseline: 1.0877x; 1.0877x over previous
//
#include <hip/hip_runtime.h>
#include <stdint.h>

typedef __bf16 bf16x8 __attribute__((ext_vector_type(8)));
typedef float f32x4 __attribute__((ext_vector_type(4)));

#define N_ROWS 4096
#define KD 128
#define BM 64
#define BN 64
#define LDA 136   // LDS row stride in bf16: 128 + 8 pad (272 B) -> 2-way bank aliasing (free, m136)
#define NCHUNK 16
#define CHUNK 256 // 4096 / NCHUNK

__device__ __forceinline__ unsigned short f32_to_bf16_rne(float f) {
    union { float f; uint32_t u; } v; v.f = f;
    uint32_t u = v.u;
    return (unsigned short)((u + 0x7FFFu + ((u >> 16) & 1u)) >> 16);
}

// One wave per row: L2-normalize, round to bf16 (RNE), pack 2 elems/lane.
__global__ __launch_bounds__(256) void normalize_kernel(const float* __restrict__ E,
                                                        unsigned short* __restrict__ out) {
    const int wave = threadIdx.x >> 6;
    const int lane = threadIdx.x & 63;
    const int row = blockIdx.x * 4 + wave;
    const float2 v = *(const float2*)&E[row * KD + lane * 2];
    float s = v.x * v.x + v.y * v.y;
#pragma unroll
    for (int m = 1; m < 64; m <<= 1) s += __shfl_xor(s, m, 64);
    float inv = 0.0f;
    if (s > 0.0f) {
        inv = rsqrtf(s);
        inv = inv * (1.5f - 0.5f * s * inv * inv);  // Newton step: ~1e-7 rel err
    }
    const unsigned short a = f32_to_bf16_rne(v.x * inv);
    const unsigned short b = f32_to_bf16_rne(v.y * inv);
    ((uint32_t*)out)[row * (KD / 2) + lane] = ((uint32_t)b << 16) | a;
}

// Block = 64-row I-tile x 256-col J-chunk. 1024 blocks = 4 blocks/CU (4 waves/SIMD).
// MFMA 16x16x32 bf16 Gram tiles, fused hardest-pos/neg epilogue, partials to ws.
__global__ __launch_bounds__(256) void gram_kernel(const unsigned short* __restrict__ Ebits,
                                                   const int* __restrict__ labels,
                                                   float* __restrict__ minpos_part,
                                                   float* __restrict__ maxneg_part) {
    __shared__ unsigned short As[BM * LDA];
    __shared__ unsigned short Bs[BN * LDA];
    __shared__ int ljs[CHUNK];

    const int tid = threadIdx.x;
    const int itile = blockIdx.x & 63;
    const int chunk = blockIdx.x >> 6;
    const int ibase = itile * BM;
    const int cbase = chunk * CHUNK;

    // Stage A-tile (64 rows x 128 bf16 = 1024 uint4, coalesced) + chunk labels.
    {
        const uint4* src = (const uint4*)(Ebits + (size_t)ibase * KD);
#pragma unroll
        for (int it = 0; it < 4; ++it) {
            const int li = tid + it * 256;
            const int r = li >> 4, c = li & 15;
            *(uint4*)&As[r * LDA + c * 8] = src[li];
        }
        ljs[tid] = labels[cbase + tid];
    }
    __syncthreads();

    const int wave = tid >> 6, lane = tid & 63;
    const int quad = lane >> 4, l15 = lane & 15;

    // A fragments: A[m=lane&15][k=quad*8+j], held in regs for the whole chunk.
    bf16x8 afrag[4];
    const unsigned short* arow = &As[(wave * 16 + l15) * LDA + quad * 8];
#pragma unroll
    for (int s = 0; s < 4; ++s) afrag[s] = *(const bf16x8*)(arow + s * 32);

    int li_lab[4];
#pragma unroll
    for (int r = 0; r < 4; ++r) li_lab[r] = labels[ibase + wave * 16 + quad * 4 + r];

    float minpos[4] = {2.0f, 2.0f, 2.0f, 2.0f};    // dots in [-1,1]; 2.0 = "no positive"
    float maxneg[4] = {-2.0f, -2.0f, -2.0f, -2.0f};

    for (int jt = 0; jt < CHUNK / BN; ++jt) {
        const int jbase = cbase + jt * BN;
        __syncthreads();  // prev iter's Bs reads done
        {
            const uint4* src = (const uint4*)(Ebits + (size_t)jbase * KD);
#pragma unroll
            for (int it = 0; it < 4; ++it) {
                const int li = tid + it * 256;
                const int r = li >> 4, c = li & 15;
                *(uint4*)&Bs[r * LDA + c * 8] = src[li];
            }
        }
        __syncthreads();

#pragma unroll
        for (int t = 0; t < 4; ++t) {
            const unsigned short* brow = &Bs[(t * 16 + l15) * LDA + quad * 8];
            f32x4 acc = {0.f, 0.f, 0.f, 0.f};
#pragma unroll
            for (int s = 0; s < 4; ++s) {
                const bf16x8 bfrag = *(const bf16x8*)(brow + s * 32);
                acc = __builtin_amdgcn_mfma_f32_16x16x32_bf16(afrag[s], bfrag, acc, 0, 0, 0);
            }
            // C/D layout: col = lane&15 (j), row = quad*4 + reg (i)  [m89/m91]
            const int jg = jbase + t * 16 + l15;
            const int lj = ljs[jt * BN + t * 16 + l15];
#pragma unroll
            for (int r = 0; r < 4; ++r) {
                const int ig = ibase + wave * 16 + quad * 4 + r;
                const float d = acc[r];
                const bool same = (lj == li_lab[r]);
                const float dp = (same && (ig != jg)) ? d : 2.0f;
                const float dn = same ? -2.0f : d;
                minpos[r] = fminf(minpos[r], dp);
                maxneg[r] = fmaxf(maxneg[r], dn);
            }
        }
    }

    // Reduce across the 16 lanes of each quad (cols); rows live in (quad,reg).
#pragma unroll
    for (int m = 1; m < 16; m <<= 1) {
#pragma unroll
        for (int r = 0; r < 4; ++r) {
            minpos[r] = fminf(minpos[r], __shfl_xor(minpos[r], m, 64));
            maxneg[r] = fmaxf(maxneg[r], __shfl_xor(maxneg[r], m, 64));
        }
    }
    if (l15 == 0) {
#pragma unroll
        for (int r = 0; r < 4; ++r) {
            const int row = ibase + wave * 16 + quad * 4 + r;
            minpos_part[row * NCHUNK + chunk] = minpos[r];
            maxneg_part[row * NCHUNK + chunk] = maxneg[r];
        }
    }
}

__global__ __launch_bounds__(256) void finalize_kernel(const float* __restrict__ minpos_part,
                                                       const float* __restrict__ maxneg_part,
                                                       float* __restrict__ out) {
    __shared__ float ssum[4];
    __shared__ int scnt[4];
    float sum = 0.f;
    int cnt = 0;
    for (int row = threadIdx.x; row < N_ROWS; row += 256) {
        float mp = 2.f, mn = -2.f;
#pragma unroll
        for (int c4 = 0; c4 < NCHUNK / 4; ++c4) {
            const float4 p = ((const float4*)minpos_part)[row * (NCHUNK / 4) + c4];
            const float4 q = ((const float4*)maxneg_part)[row * (NCHUNK / 4) + c4];
            mp = fminf(mp, fminf(fminf(p.x, p.y), fminf(p.z, p.w)));
            mn = fmaxf(mn, fmaxf(fmaxf(q.x, q.y), fmaxf(q.z, q.w)));
        }
        if (mp < 1.5f && mn > -1.5f) {  // valid: has >=1 positive and >=1 negative
            sum += fmaxf(0.f, mn - mp + 0.3f);  // relu(hp - hn + margin)
            cnt += 1;
        }
    }
#pragma unroll
    for (int m = 1; m < 64; m <<= 1) {
        sum += __shfl_xor(sum, m, 64);
        cnt += __shfl_xor(cnt, m, 64);
    }
    const int wave = threadIdx.x >> 6, lane = threadIdx.x & 63;
    if (lane == 0) { ssum[wave] = sum; scnt[wave] = cnt; }
    __syncthreads();
    if (threadIdx.x == 0) {
        const float S = ssum[0] + ssum[1] + ssum[2] + ssum[3];
        const int C = scnt[0] + scnt[1] + scnt[2] + scnt[3];
        out[0] = S / (float)(C > 0 ? C : 1);
    }
}

extern "C" void kernel_launch(void* const* d_in, const int* in_sizes, int n_in,
                              void* d_out, int out_size, void* d_ws, size_t ws_size,
                              hipStream_t stream) {
    const float* E = (const float*)d_in[0];
    const int* labels = (const int*)d_in[1];

    unsigned short* ebits = (unsigned short*)d_ws;                          // 1 MiB
    float* minpos_part = (float*)((char*)d_ws + (size_t)N_ROWS * KD * 2);   // 256 KiB
    float* maxneg_part = minpos_part + N_ROWS * NCHUNK;                     // 256 KiB
    float* out = (float*)d_out;

    normalize_kernel<<<N_ROWS / 4, 256, 0, stream>>>(E, ebits);
    gram_kernel<<<64 * NCHUNK, 256, 0, stream>>>(ebits, labels, minpos_part, maxneg_part);
    finalize_kernel<<<1, 256, 0, stream>>>(minpos_part, maxneg_part, out);
}